// Round 18
// baseline (207.889 us; speedup 1.0000x reference)
//
#include <hip/hip_runtime.h>
#include <math.h>

// ---------------- tensor-product structure ----------------------------------
#define NPATH 11
#define SROW 1152       // x1 / out row length
#define SAMP 16         // samples per tile
#define NTHREADS 512    // 8 waves
#define XT_TILE_B 39168 // bytes of one staged tile image [9][16][136] ushort

constexpr int H_L1[11]  = {0,0,0,1,1,1,1,2,2,2,2};
constexpr int H_L2[11]  = {0,1,2,0,1,1,2,0,1,2,2};
constexpr int H_LO[11]  = {0,1,2,1,0,2,1,2,1,0,2};
constexpr int H_N1[11]  = {1,1,1,3,3,3,3,5,5,5,5};
constexpr int H_N2[11]  = {1,3,5,1,3,3,5,1,3,5,5};
constexpr int H_N3[11]  = {1,3,5,3,1,5,3,5,3,1,5};
constexpr int H_PIB[12] = {0,1,2,3,6,9,12,15,20,25,30,35};  // prefix sum of N1
constexpr int H_MOFF[12]  = {0,1,4,9,18,21,36,45,70,85,90,115};
constexpr int H_W3OFF[12] = {0,1,10,35,44,53,98,143,168,213,238,363};
constexpr int H_X2OFF[3]  = {0,1,4};
constexpr int H_CBASE[3]  = {0,1,4};   // x1T column base per l1
constexpr int H_KCB[3]    = {0,1,4};   // output k-column base per lo
constexpr float H_PW[3] = {0.05103103630798288f, 0.07654655446197431f, 0.09882117688026186f};

// ================= compile-time Wigner 3j (exact port of reference) =========
namespace w3c {

constexpr double fact(int n) {
    double r = 1.0;
    for (int i = 2; i <= n; ++i) r *= (double)i;
    return r;
}

constexpr double csqrt(double x) {
    if (x <= 0.0) return 0.0;
    double g = x < 1.0 ? 1.0 : x;
    for (int i = 0; i < 100; ++i) g = 0.5 * (g + x / g);
    return g;
}

constexpr double su2_cg(int j1, int m1, int j2, int m2, int j3, int m3) {
    if (m3 != m1 + m2) return 0.0;
    int vmin = -j1 + j2 + m3;
    if (-j1 + m1 > vmin) vmin = -j1 + m1;
    if (0 > vmin) vmin = 0;
    int vmax = j2 + j3 + m1;
    if (j3 - j1 + j2 < vmax) vmax = j3 - j1 + j2;
    if (j3 + m3 < vmax) vmax = j3 + m3;
    if (vmax < vmin) return 0.0;
    double pref = (2.0 * j3 + 1.0) *
        (fact(j3 + j1 - j2) * fact(j3 - j1 + j2) * fact(j1 + j2 - j3) *
         fact(j3 + m3) * fact(j3 - m3)) /
        (fact(j1 + j2 + j3 + 1) * fact(j1 - m1) * fact(j1 + m1) *
         fact(j2 - m2) * fact(j2 + m2));
    double S = 0.0;
    for (int v = vmin; v <= vmax; ++v) {
        double sgn = ((v + j2 + m2) & 1) ? -1.0 : 1.0;
        S += sgn * (fact(j2 + j3 + m1 - v) * fact(j1 - m1 + v)) /
             (fact(v) * fact(j3 - j1 + j2 - v) * fact(j3 + m3 - v) *
              fact(v + j1 - j2 - m3));
    }
    return csqrt(pref) * S;
}

struct Q { double re[5][5]; double im[5][5]; };

constexpr Q build_q(int l) {
    Q q{};
    double s = csqrt(0.5);
    for (int m = -l; m < 0; ++m) {
        q.re[l + m][l - m] = s;
        q.im[l + m][l + m] = -s;
    }
    q.re[l][l] = 1.0;
    for (int m = 1; m <= l; ++m) {
        double sg = (m & 1) ? -1.0 : 1.0;
        q.re[l + m][l + m] = sg * s;
        q.im[l + m][l - m] = sg * s;
    }
    double fr = 1.0, fi = 0.0;
    if (l == 1) { fr = 0.0; fi = -1.0; }
    else if (l == 2) { fr = -1.0; fi = 0.0; }
    for (int r = 0; r < 5; ++r)
        for (int c = 0; c < 5; ++c) {
            double a = q.re[r][c], b = q.im[r][c];
            q.re[r][c] = a * fr - b * fi;
            q.im[r][c] = a * fi + b * fr;
        }
    return q;
}

struct PathW { float v[125]; };

constexpr PathW make_path(int l1, int l2, int l3) {
    int n1 = 2 * l1 + 1, n2 = 2 * l2 + 1, n3 = 2 * l3 + 1;
    double C[5][5][5] = {};
    for (int m1 = -l1; m1 <= l1; ++m1)
        for (int m2 = -l2; m2 <= l2; ++m2) {
            int m3 = m1 + m2;
            if (m3 >= -l3 && m3 <= l3)
                C[m1 + l1][m2 + l2][m3 + l3] = su2_cg(l1, m1, l2, m2, l3, m3);
        }
    Q q1 = build_q(l1), q2 = build_q(l2), q3 = build_q(l3);

    double Cr[5][5][5] = {}, Ci[5][5][5] = {};
    for (int j = 0; j < n1; ++j)
        for (int l = 0; l < n2; ++l)
            for (int m = 0; m < n3; ++m) {
                double ar = 0.0, ai = 0.0;
                for (int i = 0; i < n1; ++i)
                    for (int k = 0; k < n2; ++k) {
                        double t1r = q1.re[i][j], t1i = q1.im[i][j];
                        double t2r = q2.re[k][l], t2i = q2.im[k][l];
                        double tr = t1r * t2r - t1i * t2i;
                        double ti = t1r * t2i + t1i * t2r;
                        for (int n = 0; n < n3; ++n) {
                            double c = C[i][k][n];
                            if (c == 0.0) continue;
                            double pr = q3.re[n][m], pi = -q3.im[n][m];
                            ar += c * (tr * pr - ti * pi);
                            ai += c * (tr * pi + ti * pr);
                        }
                    }
                Cr[j][l][m] = ar;
                Ci[j][l][m] = ai;
            }

    double nr = 0.0, ni = 0.0;
    for (int j = 0; j < n1; ++j)
        for (int l = 0; l < n2; ++l)
            for (int m = 0; m < n3; ++m) {
                nr += Cr[j][l][m] * Cr[j][l][m];
                ni += Ci[j][l][m] * Ci[j][l][m];
            }
    nr = csqrt(nr);
    ni = csqrt(ni);
    bool useR = (nr >= ni);
    double norm = useR ? nr : ni;

    PathW out{};
    int idx = 0;
    for (int j = 0; j < n1; ++j)
        for (int l = 0; l < n2; ++l)
            for (int m = 0; m < n3; ++m)
                out.v[idx++] = (float)((useR ? Cr[j][l][m] : Ci[j][l][m]) / norm);
    return out;
}

constexpr PathW P0  = make_path(0,0,0);
constexpr PathW P1  = make_path(0,1,1);
constexpr PathW P2  = make_path(0,2,2);
constexpr PathW P3  = make_path(1,0,1);
constexpr PathW P4  = make_path(1,1,0);
constexpr PathW P5  = make_path(1,1,2);
constexpr PathW P6  = make_path(1,2,1);
constexpr PathW P7  = make_path(2,0,2);
constexpr PathW P8  = make_path(2,1,1);
constexpr PathW P9  = make_path(2,2,0);
constexpr PathW P10 = make_path(2,2,2);

struct W3All { float v[363]; };

constexpr W3All make_all() {
    W3All a{};
    const PathW* ps[11] = {&P0,&P1,&P2,&P3,&P4,&P5,&P6,&P7,&P8,&P9,&P10};
    for (int p = 0; p < 11; ++p) {
        int n = H_W3OFF[p+1] - H_W3OFF[p];
        for (int i = 0; i < n; ++i) a.v[H_W3OFF[p] + i] = ps[p]->v[i];
    }
    return a;
}

} // namespace w3c

__device__ __constant__ w3c::W3All c_W3 = w3c::make_all();

// ---------------- helpers ----------------------------------------------------
typedef float f32x4 __attribute__((ext_vector_type(4)));
typedef __bf16 bf16x8 __attribute__((ext_vector_type(8)));

__device__ __forceinline__ unsigned short f2bf(float f) {
    union { float f; unsigned int u; } v; v.f = f;
    unsigned int u = v.u + 0x7fffu + ((v.u >> 16) & 1u);   // RNE
    return (unsigned short)(u >> 16);
}

#define MFMA(a, b, c) __builtin_amdgcn_mfma_f32_16x16x32_bf16((a), (b), (c), 0, 0, 0)

// async global->LDS, 16B per lane; LDS dest = wave-uniform base + lane*16
__device__ __forceinline__ void gll16(const void* g, void* l) {
    __builtin_amdgcn_global_load_lds(
        (const __attribute__((address_space(1))) void*)g,
        (__attribute__((address_space(3))) void*)l,
        16, 0, 0);
}

// ---------------- weight prep: pure gather, hi only --------------------------
__global__ __launch_bounds__(256) void wprep_kernel(
    const float* __restrict__ w, unsigned short* __restrict__ whi)
{
    int idx = blockIdx.x * 256 + threadIdx.x;
    if (idx >= NPATH * 128 * 128) return;
    int p   = idx / 16384;
    int rem = idx - p * 16384;
    int wc  = rem >> 7;
    int u   = rem & 127;
    whi[idx] = f2bf(w[p * 16384 + u * 128 + wc]);
}

// ---------------- x1 prep: transpose+convert one tile to its LDS image -------
__global__ __launch_bounds__(256) void xprep_kernel(
    const float* __restrict__ x1, char* __restrict__ xT, long xstride,
    int N)
{
    __shared__ __align__(16) unsigned short sT[9][16][136];
    const int tile = blockIdx.x;
    const int n0   = tile * SAMP;
    const int tid  = threadIdx.x;

    // zero the pad region u in [128,136)
    for (int e = tid; e < 9 * 16 * 8; e += 256) {
        int col = e / 128, r = e % 128;
        sT[col][r / 8][128 + (r & 7)] = 0;
    }
    // transpose + convert (col/u map verified r4)
    for (int e = tid; e < SAMP * (SROW / 4); e += 256) {
        int n  = e / 288;
        int c4 = (e % 288) * 4;
        f32x4 v = (n0 + n < N) ? *(const f32x4*)&x1[(size_t)(n0 + n) * SROW + c4]
                               : (f32x4)(0.0f);
        #pragma unroll
        for (int j = 0; j < 4; ++j) {
            int c = c4 + j;
            int col, u;
            if (c < 128)       { col = 0;           u = c; }
            else if (c < 512)  { int rr = c - 128;  u = rr / 3; col = 1 + rr % 3; }
            else               { int rr = c - 512;  u = rr / 5; col = 4 + rr % 5; }
            sT[col][n][u] = f2bf(v[j]);
        }
    }
    __syncthreads();
    // linear coalesced copy LDS -> global tile image
    const char* src = (const char*)&sT[0][0][0];
    char* dst = xT + (size_t)tile * xstride;
    for (int e = tid; e < XT_TILE_B / 16; e += 256)
        *(f32x4*)(dst + e * 16) = *(const f32x4*)(src + e * 16);
}

// ---------------- tile prefetch: gll the 39168-B image into sB ---------------
__device__ __forceinline__ void prefetch_tile(
    const char* __restrict__ gsrc, unsigned char* ldst, int wid, int lane)
{
    #pragma unroll
    for (int c = 0; c < 5; ++c) {
        const int chunk = wid + c * 8;          // 0..39
        if (chunk < 38) {
            gll16(gsrc + chunk * 1024 + lane * 16, ldst + chunk * 1024);
        } else if (chunk == 38) {
            if (lane < 16)                       // partial 256-B chunk
                gll16(gsrc + 38 * 1024 + lane * 16, ldst + 38 * 1024);
        }
    }
}

// ---------------- sM35 staging (verified r4, byte-identical) -----------------
__device__ __forceinline__ void stage_m35(
    const float* __restrict__ x2, int n0, int N, float* sM35, int tid)
{
    for (int e = tid; e < SAMP * 115; e += NTHREADS) {
        int n = e / 115, m = e % 115;
        float val = 0.0f;
        int pi5 = 0;
        #pragma unroll
        for (int p = 0; p < NPATH; ++p) {
            if (m >= H_MOFF[p] && m < H_MOFF[p + 1]) {
                const int n2 = H_N2[p], n3 = H_N3[p];
                int rr = m - H_MOFF[p];
                int i = rr / n3, k = rr % n3;
                if (n0 + n < N) {
                    const float* Cp  = c_W3.v + H_W3OFF[p];
                    const float* x2p = x2 + (size_t)(n0 + n) * 9 + H_X2OFF[H_L2[p]];
                    float a = 0.0f;
                    #pragma unroll
                    for (int j = 0; j < n2; ++j)
                        a += Cp[(i * n2 + j) * n3 + k] * x2p[j];
                    val = H_PW[H_LO[p]] * a;
                }
                pi5 = (H_PIB[p] + i) * 5 + k;
            }
        }
        sM35[n * 175 + pi5] = val;
    }
}

// ---------------- GEMM pass (W hi-only; indices verified r7/r8/r11) ----------
template<int P0G, int NP, int CB, int NC>
__device__ __forceinline__ void gemm_pass(
    const unsigned short* __restrict__ whi,
    const unsigned short (*sB)[16][136],
    const float* sM35,
    float (&ov)[4][9], int r16, int q4, int wt)
{
    f32x4 acc[NP][NC];
    #pragma unroll
    for (int pp = 0; pp < NP; ++pp)
        #pragma unroll
        for (int i = 0; i < NC; ++i) acc[pp][i] = (f32x4)(0.0f);

    #pragma unroll
    for (int ub = 0; ub < 4; ++ub) {
        const int ko = ub * 32 + q4 * 8;
        bf16x8 B[NC];
        #pragma unroll
        for (int c = 0; c < NC; ++c)
            B[c] = *(const bf16x8*)&sB[CB + c][r16][ko];
        #pragma unroll
        for (int pp = 0; pp < NP; ++pp) {
            const size_t aoff =
                ((size_t)((P0G + pp) * 128 + wt * 16 + r16)) * 128 + ko;
            bf16x8 Ah = *(const bf16x8*)&whi[aoff];
            #pragma unroll
            for (int i = 0; i < NC; ++i)
                acc[pp][i] = MFMA(Ah, B[i], acc[pp][i]);
        }
    }

    #pragma unroll
    for (int pp = 0; pp < NP; ++pp) {
        const int P = P0G + pp;
        #pragma unroll
        for (int i = 0; i < NC; ++i)
            #pragma unroll
            for (int k = 0; k < H_N3[P]; ++k) {
                const float mv = sM35[r16 * 175 + (H_PIB[P] + i) * 5 + k];
                #pragma unroll
                for (int r = 0; r < 4; ++r)
                    ov[r][H_KCB[H_LO[P]] + k] += acc[pp][i][r] * mv;
            }
    }
}

// ---------------- main kernel: r14 flow, barrier-free scattered epilogue -----
// LDS: sB 39168 + sM35 11200 = 50368 B.
// After the GEMM each lane stores its own 36 ov values directly to global
// (scalar dwords, compile-time offsets off 3 base pointers). The block
// collectively covers contiguous channel panels, so L2 write-back merges
// the scatter into full lines. Zero barriers after staging.
__global__ __launch_bounds__(NTHREADS, 1) void fctp_kernel(
    const float* __restrict__ x2,
    const unsigned short* __restrict__ whi,
    const char* __restrict__ xT, long xstride,
    float* __restrict__ out, int N)
{
    __shared__ __align__(16) unsigned char smem[50368];
    const unsigned short (*sB)[16][136] = (const unsigned short (*)[16][136])smem;
    float* sM35 = (float*)(smem + 39168);

    const int tid  = threadIdx.x;
    const int lane = tid & 63;
    const int wt   = tid >> 6;
    const int r16  = lane & 15;
    const int q4   = lane >> 4;
    const int tile = blockIdx.x;
    const int n0   = tile * SAMP;

    // ---- stage: async gll of pre-transposed image + sM35 compute ----
    prefetch_tile(xT + (size_t)tile * xstride, smem, wt, lane);
    stage_m35(x2, n0, N, sM35, tid);
    __syncthreads();   // drains gll (vmcnt0) + ds

    // ---- MFMA GEMM in 5 l1-homogeneous passes (W hi-only) ----
    float ov[4][9];
    #pragma unroll
    for (int r = 0; r < 4; ++r)
        #pragma unroll
        for (int j = 0; j < 9; ++j) ov[r][j] = 0.0f;

    gemm_pass<0, 3, 0, 1>(whi, sB, sM35, ov, r16, q4, wt);  // p0-2, col 0
    gemm_pass<3, 2, 1, 3>(whi, sB, sM35, ov, r16, q4, wt);  // p3,4 cols 1-3
    gemm_pass<5, 2, 1, 3>(whi, sB, sM35, ov, r16, q4, wt);  // p5,6 cols 1-3
    gemm_pass<7, 2, 4, 5>(whi, sB, sM35, ov, r16, q4, wt);  // p7,8 cols 4-8
    gemm_pass<9, 2, 4, 5>(whi, sB, sM35, ov, r16, q4, wt);  // p9,10 cols 4-8

    // ---- barrier-free scattered epilogue (verified output map r4/r7) ----
    const int n = n0 + r16;
    if (n < N) {
        const int wbase = wt * 16 + q4 * 4;
        float* o  = &out[(size_t)n * SROW];
        float* o0 = &o[wbase];            // lo=0: w = wbase+r
        float* o1 = &o[128 + wbase * 3];  // lo=1: (wbase+r)*3 + kk
        float* o2 = &o[512 + wbase * 5];  // lo=2: (wbase+r)*5 + kk
        #pragma unroll
        for (int r = 0; r < 4; ++r) {
            o0[r] = ov[r][0];
            #pragma unroll
            for (int kk = 0; kk < 3; ++kk) o1[r * 3 + kk] = ov[r][1 + kk];
            #pragma unroll
            for (int kk = 0; kk < 5; ++kk) o2[r * 5 + kk] = ov[r][4 + kk];
        }
    }
}

// ---------------- launch -----------------------------------------------------
extern "C" void kernel_launch(void* const* d_in, const int* in_sizes, int n_in,
                              void* d_out, int out_size, void* d_ws, size_t ws_size,
                              hipStream_t stream) {
    const float* x1 = (const float*)d_in[0];
    const float* x2 = (const float*)d_in[1];
    const float* wt = (const float*)d_in[2];
    float* out = (float*)d_out;

    unsigned short* whi = (unsigned short*)d_ws;

    int N = in_sizes[0] / SROW;
    int ntiles = (N + SAMP - 1) / SAMP;

    size_t whiB = (size_t)NPATH * 128 * 128 * sizeof(unsigned short);
    size_t xtB  = (size_t)ntiles * XT_TILE_B;
    char* xT;
    long  xstride;
    if (ws_size >= whiB + xtB) {
        xT = (char*)d_ws + whiB;
        xstride = XT_TILE_B;
    } else {
        // park each tile's image inside its own (not-yet-written) output region;
        // the owning block consumes it before writing that region.
        xT = (char*)d_out;
        xstride = (long)SAMP * SROW * 4;   // 73728 >= 39168
    }

    hipLaunchKernelGGL(wprep_kernel, dim3((NPATH * 128 * 128 + 255) / 256),
                       dim3(256), 0, stream, wt, whi);
    hipLaunchKernelGGL(xprep_kernel, dim3(ntiles), dim3(256), 0, stream,
                       x1, xT, xstride, N);

    hipLaunchKernelGGL(fctp_kernel, dim3(ntiles), dim3(NTHREADS), 0, stream,
                       x2, whi, xT, xstride, out, N);
}

// Round 19
// 137.269 us; speedup vs baseline: 1.5145x; 1.5145x over previous
//
#include <hip/hip_runtime.h>
#include <math.h>

// ---------------- tensor-product structure ----------------------------------
#define NPATH 11
#define SROW 1152        // x1 / out row length
#define SAMP 16          // samples per tile
#define NTHREADS 512     // 8 waves
#define XT2_TILE_B 36864 // fragment-major tile image: [9][4][64 lanes][16B]

constexpr int H_L1[11]  = {0,0,0,1,1,1,1,2,2,2,2};
constexpr int H_L2[11]  = {0,1,2,0,1,1,2,0,1,2,2};
constexpr int H_LO[11]  = {0,1,2,1,0,2,1,2,1,0,2};
constexpr int H_N1[11]  = {1,1,1,3,3,3,3,5,5,5,5};
constexpr int H_N2[11]  = {1,3,5,1,3,3,5,1,3,5,5};
constexpr int H_N3[11]  = {1,3,5,3,1,5,3,5,3,1,5};
constexpr int H_PIB[12] = {0,1,2,3,6,9,12,15,20,25,30,35};  // prefix sum of N1
constexpr int H_MOFF[12]  = {0,1,4,9,18,21,36,45,70,85,90,115};
constexpr int H_W3OFF[12] = {0,1,10,35,44,53,98,143,168,213,238,363};
constexpr int H_X2OFF[3]  = {0,1,4};
constexpr int H_CBASE[3]  = {0,1,4};   // x1T column base per l1
constexpr int H_KCB[3]    = {0,1,4};   // output k-column base per lo
constexpr float H_PW[3] = {0.05103103630798288f, 0.07654655446197431f, 0.09882117688026186f};

// ================= compile-time Wigner 3j (exact port of reference) =========
namespace w3c {

constexpr double fact(int n) {
    double r = 1.0;
    for (int i = 2; i <= n; ++i) r *= (double)i;
    return r;
}

constexpr double csqrt(double x) {
    if (x <= 0.0) return 0.0;
    double g = x < 1.0 ? 1.0 : x;
    for (int i = 0; i < 100; ++i) g = 0.5 * (g + x / g);
    return g;
}

constexpr double su2_cg(int j1, int m1, int j2, int m2, int j3, int m3) {
    if (m3 != m1 + m2) return 0.0;
    int vmin = -j1 + j2 + m3;
    if (-j1 + m1 > vmin) vmin = -j1 + m1;
    if (0 > vmin) vmin = 0;
    int vmax = j2 + j3 + m1;
    if (j3 - j1 + j2 < vmax) vmax = j3 - j1 + j2;
    if (j3 + m3 < vmax) vmax = j3 + m3;
    if (vmax < vmin) return 0.0;
    double pref = (2.0 * j3 + 1.0) *
        (fact(j3 + j1 - j2) * fact(j3 - j1 + j2) * fact(j1 + j2 - j3) *
         fact(j3 + m3) * fact(j3 - m3)) /
        (fact(j1 + j2 + j3 + 1) * fact(j1 - m1) * fact(j1 + m1) *
         fact(j2 - m2) * fact(j2 + m2));
    double S = 0.0;
    for (int v = vmin; v <= vmax; ++v) {
        double sgn = ((v + j2 + m2) & 1) ? -1.0 : 1.0;
        S += sgn * (fact(j2 + j3 + m1 - v) * fact(j1 - m1 + v)) /
             (fact(v) * fact(j3 - j1 + j2 - v) * fact(j3 + m3 - v) *
              fact(v + j1 - j2 - m3));
    }
    return csqrt(pref) * S;
}

struct Q { double re[5][5]; double im[5][5]; };

constexpr Q build_q(int l) {
    Q q{};
    double s = csqrt(0.5);
    for (int m = -l; m < 0; ++m) {
        q.re[l + m][l - m] = s;
        q.im[l + m][l + m] = -s;
    }
    q.re[l][l] = 1.0;
    for (int m = 1; m <= l; ++m) {
        double sg = (m & 1) ? -1.0 : 1.0;
        q.re[l + m][l + m] = sg * s;
        q.im[l + m][l - m] = sg * s;
    }
    double fr = 1.0, fi = 0.0;
    if (l == 1) { fr = 0.0; fi = -1.0; }
    else if (l == 2) { fr = -1.0; fi = 0.0; }
    for (int r = 0; r < 5; ++r)
        for (int c = 0; c < 5; ++c) {
            double a = q.re[r][c], b = q.im[r][c];
            q.re[r][c] = a * fr - b * fi;
            q.im[r][c] = a * fi + b * fr;
        }
    return q;
}

struct PathW { float v[125]; };

constexpr PathW make_path(int l1, int l2, int l3) {
    int n1 = 2 * l1 + 1, n2 = 2 * l2 + 1, n3 = 2 * l3 + 1;
    double C[5][5][5] = {};
    for (int m1 = -l1; m1 <= l1; ++m1)
        for (int m2 = -l2; m2 <= l2; ++m2) {
            int m3 = m1 + m2;
            if (m3 >= -l3 && m3 <= l3)
                C[m1 + l1][m2 + l2][m3 + l3] = su2_cg(l1, m1, l2, m2, l3, m3);
        }
    Q q1 = build_q(l1), q2 = build_q(l2), q3 = build_q(l3);

    double Cr[5][5][5] = {}, Ci[5][5][5] = {};
    for (int j = 0; j < n1; ++j)
        for (int l = 0; l < n2; ++l)
            for (int m = 0; m < n3; ++m) {
                double ar = 0.0, ai = 0.0;
                for (int i = 0; i < n1; ++i)
                    for (int k = 0; k < n2; ++k) {
                        double t1r = q1.re[i][j], t1i = q1.im[i][j];
                        double t2r = q2.re[k][l], t2i = q2.im[k][l];
                        double tr = t1r * t2r - t1i * t2i;
                        double ti = t1r * t2i + t1i * t2r;
                        for (int n = 0; n < n3; ++n) {
                            double c = C[i][k][n];
                            if (c == 0.0) continue;
                            double pr = q3.re[n][m], pi = -q3.im[n][m];
                            ar += c * (tr * pr - ti * pi);
                            ai += c * (tr * pi + ti * pr);
                        }
                    }
                Cr[j][l][m] = ar;
                Ci[j][l][m] = ai;
            }

    double nr = 0.0, ni = 0.0;
    for (int j = 0; j < n1; ++j)
        for (int l = 0; l < n2; ++l)
            for (int m = 0; m < n3; ++m) {
                nr += Cr[j][l][m] * Cr[j][l][m];
                ni += Ci[j][l][m] * Ci[j][l][m];
            }
    nr = csqrt(nr);
    ni = csqrt(ni);
    bool useR = (nr >= ni);
    double norm = useR ? nr : ni;

    PathW out{};
    int idx = 0;
    for (int j = 0; j < n1; ++j)
        for (int l = 0; l < n2; ++l)
            for (int m = 0; m < n3; ++m)
                out.v[idx++] = (float)((useR ? Cr[j][l][m] : Ci[j][l][m]) / norm);
    return out;
}

constexpr PathW P0  = make_path(0,0,0);
constexpr PathW P1  = make_path(0,1,1);
constexpr PathW P2  = make_path(0,2,2);
constexpr PathW P3  = make_path(1,0,1);
constexpr PathW P4  = make_path(1,1,0);
constexpr PathW P5  = make_path(1,1,2);
constexpr PathW P6  = make_path(1,2,1);
constexpr PathW P7  = make_path(2,0,2);
constexpr PathW P8  = make_path(2,1,1);
constexpr PathW P9  = make_path(2,2,0);
constexpr PathW P10 = make_path(2,2,2);

struct W3All { float v[363]; };

constexpr W3All make_all() {
    W3All a{};
    const PathW* ps[11] = {&P0,&P1,&P2,&P3,&P4,&P5,&P6,&P7,&P8,&P9,&P10};
    for (int p = 0; p < 11; ++p) {
        int n = H_W3OFF[p+1] - H_W3OFF[p];
        for (int i = 0; i < n; ++i) a.v[H_W3OFF[p] + i] = ps[p]->v[i];
    }
    return a;
}

} // namespace w3c

__device__ __constant__ w3c::W3All c_W3 = w3c::make_all();

// ---------------- helpers ----------------------------------------------------
typedef float f32x4 __attribute__((ext_vector_type(4)));
typedef __bf16 bf16x8 __attribute__((ext_vector_type(8)));

__device__ __forceinline__ unsigned short f2bf(float f) {
    union { float f; unsigned int u; } v; v.f = f;
    unsigned int u = v.u + 0x7fffu + ((v.u >> 16) & 1u);   // RNE
    return (unsigned short)(u >> 16);
}

#define MFMA(a, b, c) __builtin_amdgcn_mfma_f32_16x16x32_bf16((a), (b), (c), 0, 0, 0)

// ---------------- weight prep: pure gather, hi only --------------------------
__global__ __launch_bounds__(256) void wprep_kernel(
    const float* __restrict__ w, unsigned short* __restrict__ whi)
{
    int idx = blockIdx.x * 256 + threadIdx.x;
    if (idx >= NPATH * 128 * 128) return;
    int p   = idx / 16384;
    int rem = idx - p * 16384;
    int wc  = rem >> 7;
    int u   = rem & 127;
    whi[idx] = f2bf(w[p * 16384 + u * 128 + wc]);
}

// ---------------- x1 prep: transpose+convert -> FRAGMENT-MAJOR image ---------
// Layout: offset ((col*4 + ub)*64 + lane)*16  holds the 16B B-fragment that
// lane (r16 = lane&15, q4 = lane>>4) consumes at (col, ub). A wave's B-read
// is one fully coalesced 1 KB block.
__global__ __launch_bounds__(256) void xprep_kernel(
    const float* __restrict__ x1, char* __restrict__ xT, long xstride,
    int N)
{
    __shared__ __align__(16) unsigned short sT[9][16][128];  // 36864 B, no pad
    const int tile = blockIdx.x;
    const int n0   = tile * SAMP;
    const int tid  = threadIdx.x;

    // transpose + convert (col/u map verified r4)
    for (int e = tid; e < SAMP * (SROW / 4); e += 256) {
        int n  = e / 288;
        int c4 = (e % 288) * 4;
        f32x4 v = (n0 + n < N) ? *(const f32x4*)&x1[(size_t)(n0 + n) * SROW + c4]
                               : (f32x4)(0.0f);
        #pragma unroll
        for (int j = 0; j < 4; ++j) {
            int c = c4 + j;
            int col, u;
            if (c < 128)       { col = 0;           u = c; }
            else if (c < 512)  { int rr = c - 128;  u = rr / 3; col = 1 + rr % 3; }
            else               { int rr = c - 512;  u = rr / 5; col = 4 + rr % 5; }
            sT[col][n][u] = f2bf(v[j]);
        }
    }
    __syncthreads();

    // fragment-major copy LDS -> global tile image (coalesced 16B stores)
    char* dst = xT + (size_t)tile * xstride;
    for (int e = tid; e < 9 * 4 * 64; e += 256) {
        int col  = e >> 8;
        int ub   = (e >> 6) & 3;
        int lane = e & 63;
        int r16 = lane & 15, q4 = lane >> 4;
        const unsigned short* s = &sT[col][r16][ub * 32 + q4 * 8];
        *(f32x4*)(dst + e * 16) = *(const f32x4*)s;
    }
}

// ---------------- sM35 staging (verified r4, byte-identical) -----------------
__device__ __forceinline__ void stage_m35(
    const float* __restrict__ x2, int n0, int N, float* sM35, int tid)
{
    for (int e = tid; e < SAMP * 115; e += NTHREADS) {
        int n = e / 115, m = e % 115;
        float val = 0.0f;
        int pi5 = 0;
        #pragma unroll
        for (int p = 0; p < NPATH; ++p) {
            if (m >= H_MOFF[p] && m < H_MOFF[p + 1]) {
                const int n2 = H_N2[p], n3 = H_N3[p];
                int rr = m - H_MOFF[p];
                int i = rr / n3, k = rr % n3;
                if (n0 + n < N) {
                    const float* Cp  = c_W3.v + H_W3OFF[p];
                    const float* x2p = x2 + (size_t)(n0 + n) * 9 + H_X2OFF[H_L2[p]];
                    float a = 0.0f;
                    #pragma unroll
                    for (int j = 0; j < n2; ++j)
                        a += Cp[(i * n2 + j) * n3 + k] * x2p[j];
                    val = H_PW[H_LO[p]] * a;
                }
                pi5 = (H_PIB[p] + i) * 5 + k;
            }
        }
        sM35[n * 175 + pi5] = val;
    }
}

// ---------------- GEMM pass: B direct from global (fragment-major) -----------
// Indices verified r7/r8/r11; only the B source changed (LDS -> global/L1).
template<int P0G, int NP, int CB, int NC>
__device__ __forceinline__ void gemm_pass(
    const unsigned short* __restrict__ whi,
    const char* __restrict__ xt,      // fragment-major tile base
    const float* sM35,
    float (&ov)[4][9], int r16, int q4, int wt, int lane)
{
    f32x4 acc[NP][NC];
    #pragma unroll
    for (int pp = 0; pp < NP; ++pp)
        #pragma unroll
        for (int i = 0; i < NC; ++i) acc[pp][i] = (f32x4)(0.0f);

    #pragma unroll
    for (int ub = 0; ub < 4; ++ub) {
        const int ko = ub * 32 + q4 * 8;
        bf16x8 B[NC];
        #pragma unroll
        for (int c = 0; c < NC; ++c)
            B[c] = *(const bf16x8*)(xt + (((CB + c) * 4 + ub) << 10) + lane * 16);
        #pragma unroll
        for (int pp = 0; pp < NP; ++pp) {
            const size_t aoff =
                ((size_t)((P0G + pp) * 128 + wt * 16 + r16)) * 128 + ko;
            bf16x8 Ah = *(const bf16x8*)&whi[aoff];
            #pragma unroll
            for (int i = 0; i < NC; ++i)
                acc[pp][i] = MFMA(Ah, B[i], acc[pp][i]);
        }
    }

    #pragma unroll
    for (int pp = 0; pp < NP; ++pp) {
        const int P = P0G + pp;
        #pragma unroll
        for (int i = 0; i < NC; ++i)
            #pragma unroll
            for (int k = 0; k < H_N3[P]; ++k) {
                const float mv = sM35[r16 * 175 + (H_PIB[P] + i) * 5 + k];
                #pragma unroll
                for (int r = 0; r < 4; ++r)
                    ov[r][H_KCB[H_LO[P]] + k] += acc[pp][i][r] * mv;
            }
    }
}

// ---------------- main kernel: no LDS B staging, 3 barriers total ------------
// LDS union: sM35 (11200 B, live during GEMM) then sOut[16][1156] (73984 B).
__global__ __launch_bounds__(NTHREADS, 1) void fctp_kernel(
    const float* __restrict__ x2,
    const unsigned short* __restrict__ whi,
    const char* __restrict__ xT, long xstride,
    float* __restrict__ out, int N)
{
    __shared__ __align__(16) unsigned char smem[73984];
    float* sM35 = (float*)smem;

    const int tid  = threadIdx.x;
    const int lane = tid & 63;
    const int wt   = tid >> 6;
    const int r16  = lane & 15;
    const int q4   = lane >> 4;
    const int tile = blockIdx.x;
    const int n0   = tile * SAMP;
    const char* xt = xT + (size_t)tile * xstride;

    // ---- stage sM35 only (no B staging needed) ----
    stage_m35(x2, n0, N, sM35, tid);
    __syncthreads();

    // ---- MFMA GEMM in 5 l1-homogeneous passes, B from global/L1 ----
    float ov[4][9];
    #pragma unroll
    for (int r = 0; r < 4; ++r)
        #pragma unroll
        for (int j = 0; j < 9; ++j) ov[r][j] = 0.0f;

    gemm_pass<0, 3, 0, 1>(whi, xt, sM35, ov, r16, q4, wt, lane);  // p0-2
    gemm_pass<3, 2, 1, 3>(whi, xt, sM35, ov, r16, q4, wt, lane);  // p3,4
    gemm_pass<5, 2, 1, 3>(whi, xt, sM35, ov, r16, q4, wt, lane);  // p5,6
    gemm_pass<7, 2, 4, 5>(whi, xt, sM35, ov, r16, q4, wt, lane);  // p7,8
    gemm_pass<9, 2, 4, 5>(whi, xt, sM35, ov, r16, q4, wt, lane);  // p9,10

    // ---- single-phase epilogue: sOut[16][1156] aliases the union ----
    __syncthreads();   // all sM35 reads complete
    float* sOut = (float*)smem;
    {
        const int wbase = wt * 16 + q4 * 4;
        float* so = &sOut[r16 * 1156];
        #pragma unroll
        for (int r = 0; r < 4; ++r) {
            const int w = wbase + r;
            so[w] = ov[r][0];
            #pragma unroll
            for (int kk = 0; kk < 3; ++kk) so[128 + w * 3 + kk] = ov[r][1 + kk];
            #pragma unroll
            for (int kk = 0; kk < 5; ++kk) so[512 + w * 5 + kk] = ov[r][4 + kk];
        }
    }
    __syncthreads();

    for (int e = tid; e < SAMP * (SROW / 4); e += NTHREADS) {
        int nn = e / (SROW / 4), c4 = (e % (SROW / 4)) * 4;
        int gn = n0 + nn;
        if (gn < N)
            *(f32x4*)&out[(size_t)gn * SROW + c4] =
                *(const f32x4*)&sOut[nn * 1156 + c4];
    }
}

// ---------------- launch -----------------------------------------------------
extern "C" void kernel_launch(void* const* d_in, const int* in_sizes, int n_in,
                              void* d_out, int out_size, void* d_ws, size_t ws_size,
                              hipStream_t stream) {
    const float* x1 = (const float*)d_in[0];
    const float* x2 = (const float*)d_in[1];
    const float* wt = (const float*)d_in[2];
    float* out = (float*)d_out;

    unsigned short* whi = (unsigned short*)d_ws;

    int N = in_sizes[0] / SROW;
    int ntiles = (N + SAMP - 1) / SAMP;

    size_t whiB = (size_t)NPATH * 128 * 128 * sizeof(unsigned short);
    size_t xtB  = (size_t)ntiles * XT2_TILE_B;
    char* xT;
    long  xstride;
    if (ws_size >= whiB + xtB) {
        xT = (char*)d_ws + whiB;
        xstride = XT2_TILE_B;
    } else {
        // park each tile's image inside its own (not-yet-written) output region;
        // the owning block consumes it before writing that region.
        xT = (char*)d_out;
        xstride = (long)SAMP * SROW * 4;   // 73728 >= 36864
    }

    hipLaunchKernelGGL(wprep_kernel, dim3((NPATH * 128 * 128 + 255) / 256),
                       dim3(256), 0, stream, wt, whi);
    hipLaunchKernelGGL(xprep_kernel, dim3(ntiles), dim3(256), 0, stream,
                       x1, xT, xstride, N);

    hipLaunchKernelGGL(fctp_kernel, dim3(ntiles), dim3(NTHREADS), 0, stream,
                       x2, whi, xT, xstride, out, N);
}

// Round 20
// 137.128 us; speedup vs baseline: 1.5160x; 1.0010x over previous
//
#include <hip/hip_runtime.h>
#include <math.h>

// ---------------- tensor-product structure ----------------------------------
#define NPATH 11
#define SROW 1152        // x1 / out row length
#define SAMP 16          // samples per tile
#define NTHREADS 512     // 8 waves
#define XT2_TILE_B 36864 // fragment-major tile image: [9][4][64 lanes][16B]

constexpr int H_L1[11]  = {0,0,0,1,1,1,1,2,2,2,2};
constexpr int H_L2[11]  = {0,1,2,0,1,1,2,0,1,2,2};
constexpr int H_LO[11]  = {0,1,2,1,0,2,1,2,1,0,2};
constexpr int H_N1[11]  = {1,1,1,3,3,3,3,5,5,5,5};
constexpr int H_N2[11]  = {1,3,5,1,3,3,5,1,3,5,5};
constexpr int H_N3[11]  = {1,3,5,3,1,5,3,5,3,1,5};
constexpr int H_PIB[12] = {0,1,2,3,6,9,12,15,20,25,30,35};  // prefix sum of N1
constexpr int H_MOFF[12]  = {0,1,4,9,18,21,36,45,70,85,90,115};
constexpr int H_W3OFF[12] = {0,1,10,35,44,53,98,143,168,213,238,363};
constexpr int H_X2OFF[3]  = {0,1,4};
constexpr int H_CBASE[3]  = {0,1,4};   // x1T column base per l1
constexpr int H_KCB[3]    = {0,1,4};   // output k-column base per lo
constexpr float H_PW[3] = {0.05103103630798288f, 0.07654655446197431f, 0.09882117688026186f};

// ================= compile-time Wigner 3j (exact port of reference) =========
namespace w3c {

constexpr double fact(int n) {
    double r = 1.0;
    for (int i = 2; i <= n; ++i) r *= (double)i;
    return r;
}

constexpr double csqrt(double x) {
    if (x <= 0.0) return 0.0;
    double g = x < 1.0 ? 1.0 : x;
    for (int i = 0; i < 100; ++i) g = 0.5 * (g + x / g);
    return g;
}

constexpr double su2_cg(int j1, int m1, int j2, int m2, int j3, int m3) {
    if (m3 != m1 + m2) return 0.0;
    int vmin = -j1 + j2 + m3;
    if (-j1 + m1 > vmin) vmin = -j1 + m1;
    if (0 > vmin) vmin = 0;
    int vmax = j2 + j3 + m1;
    if (j3 - j1 + j2 < vmax) vmax = j3 - j1 + j2;
    if (j3 + m3 < vmax) vmax = j3 + m3;
    if (vmax < vmin) return 0.0;
    double pref = (2.0 * j3 + 1.0) *
        (fact(j3 + j1 - j2) * fact(j3 - j1 + j2) * fact(j1 + j2 - j3) *
         fact(j3 + m3) * fact(j3 - m3)) /
        (fact(j1 + j2 + j3 + 1) * fact(j1 - m1) * fact(j1 + m1) *
         fact(j2 - m2) * fact(j2 + m2));
    double S = 0.0;
    for (int v = vmin; v <= vmax; ++v) {
        double sgn = ((v + j2 + m2) & 1) ? -1.0 : 1.0;
        S += sgn * (fact(j2 + j3 + m1 - v) * fact(j1 - m1 + v)) /
             (fact(v) * fact(j3 - j1 + j2 - v) * fact(j3 + m3 - v) *
              fact(v + j1 - j2 - m3));
    }
    return csqrt(pref) * S;
}

struct Q { double re[5][5]; double im[5][5]; };

constexpr Q build_q(int l) {
    Q q{};
    double s = csqrt(0.5);
    for (int m = -l; m < 0; ++m) {
        q.re[l + m][l - m] = s;
        q.im[l + m][l + m] = -s;
    }
    q.re[l][l] = 1.0;
    for (int m = 1; m <= l; ++m) {
        double sg = (m & 1) ? -1.0 : 1.0;
        q.re[l + m][l + m] = sg * s;
        q.im[l + m][l - m] = sg * s;
    }
    double fr = 1.0, fi = 0.0;
    if (l == 1) { fr = 0.0; fi = -1.0; }
    else if (l == 2) { fr = -1.0; fi = 0.0; }
    for (int r = 0; r < 5; ++r)
        for (int c = 0; c < 5; ++c) {
            double a = q.re[r][c], b = q.im[r][c];
            q.re[r][c] = a * fr - b * fi;
            q.im[r][c] = a * fi + b * fr;
        }
    return q;
}

struct PathW { float v[125]; };

constexpr PathW make_path(int l1, int l2, int l3) {
    int n1 = 2 * l1 + 1, n2 = 2 * l2 + 1, n3 = 2 * l3 + 1;
    double C[5][5][5] = {};
    for (int m1 = -l1; m1 <= l1; ++m1)
        for (int m2 = -l2; m2 <= l2; ++m2) {
            int m3 = m1 + m2;
            if (m3 >= -l3 && m3 <= l3)
                C[m1 + l1][m2 + l2][m3 + l3] = su2_cg(l1, m1, l2, m2, l3, m3);
        }
    Q q1 = build_q(l1), q2 = build_q(l2), q3 = build_q(l3);

    double Cr[5][5][5] = {}, Ci[5][5][5] = {};
    for (int j = 0; j < n1; ++j)
        for (int l = 0; l < n2; ++l)
            for (int m = 0; m < n3; ++m) {
                double ar = 0.0, ai = 0.0;
                for (int i = 0; i < n1; ++i)
                    for (int k = 0; k < n2; ++k) {
                        double t1r = q1.re[i][j], t1i = q1.im[i][j];
                        double t2r = q2.re[k][l], t2i = q2.im[k][l];
                        double tr = t1r * t2r - t1i * t2i;
                        double ti = t1r * t2i + t1i * t2r;
                        for (int n = 0; n < n3; ++n) {
                            double c = C[i][k][n];
                            if (c == 0.0) continue;
                            double pr = q3.re[n][m], pi = -q3.im[n][m];
                            ar += c * (tr * pr - ti * pi);
                            ai += c * (tr * pi + ti * pr);
                        }
                    }
                Cr[j][l][m] = ar;
                Ci[j][l][m] = ai;
            }

    double nr = 0.0, ni = 0.0;
    for (int j = 0; j < n1; ++j)
        for (int l = 0; l < n2; ++l)
            for (int m = 0; m < n3; ++m) {
                nr += Cr[j][l][m] * Cr[j][l][m];
                ni += Ci[j][l][m] * Ci[j][l][m];
            }
    nr = csqrt(nr);
    ni = csqrt(ni);
    bool useR = (nr >= ni);
    double norm = useR ? nr : ni;

    PathW out{};
    int idx = 0;
    for (int j = 0; j < n1; ++j)
        for (int l = 0; l < n2; ++l)
            for (int m = 0; m < n3; ++m)
                out.v[idx++] = (float)((useR ? Cr[j][l][m] : Ci[j][l][m]) / norm);
    return out;
}

constexpr PathW P0  = make_path(0,0,0);
constexpr PathW P1  = make_path(0,1,1);
constexpr PathW P2  = make_path(0,2,2);
constexpr PathW P3  = make_path(1,0,1);
constexpr PathW P4  = make_path(1,1,0);
constexpr PathW P5  = make_path(1,1,2);
constexpr PathW P6  = make_path(1,2,1);
constexpr PathW P7  = make_path(2,0,2);
constexpr PathW P8  = make_path(2,1,1);
constexpr PathW P9  = make_path(2,2,0);
constexpr PathW P10 = make_path(2,2,2);

struct W3All { float v[363]; };

constexpr W3All make_all() {
    W3All a{};
    const PathW* ps[11] = {&P0,&P1,&P2,&P3,&P4,&P5,&P6,&P7,&P8,&P9,&P10};
    for (int p = 0; p < 11; ++p) {
        int n = H_W3OFF[p+1] - H_W3OFF[p];
        for (int i = 0; i < n; ++i) a.v[H_W3OFF[p] + i] = ps[p]->v[i];
    }
    return a;
}

} // namespace w3c

__device__ __constant__ w3c::W3All c_W3 = w3c::make_all();

// ---------------- helpers ----------------------------------------------------
typedef float f32x4 __attribute__((ext_vector_type(4)));
typedef __bf16 bf16x8 __attribute__((ext_vector_type(8)));

__device__ __forceinline__ unsigned short f2bf(float f) {
    union { float f; unsigned int u; } v; v.f = f;
    unsigned int u = v.u + 0x7fffu + ((v.u >> 16) & 1u);   // RNE
    return (unsigned short)(u >> 16);
}

#define MFMA(a, b, c) __builtin_amdgcn_mfma_f32_16x16x32_bf16((a), (b), (c), 0, 0, 0)

// ---------------- weight prep: pure gather, hi only --------------------------
__global__ __launch_bounds__(256) void wprep_kernel(
    const float* __restrict__ w, unsigned short* __restrict__ whi)
{
    int idx = blockIdx.x * 256 + threadIdx.x;
    if (idx >= NPATH * 128 * 128) return;
    int p   = idx / 16384;
    int rem = idx - p * 16384;
    int wc  = rem >> 7;
    int u   = rem & 127;
    whi[idx] = f2bf(w[p * 16384 + u * 128 + wc]);
}

// ---------------- x1 prep: transpose+convert -> FRAGMENT-MAJOR image ---------
// Layout: offset ((col*4 + ub)*64 + lane)*16 holds the 16B B-fragment that
// lane (r16 = lane&15, q4 = lane>>4) consumes at (col, ub).
__global__ __launch_bounds__(256) void xprep_kernel(
    const float* __restrict__ x1, char* __restrict__ xT, long xstride,
    int N)
{
    __shared__ __align__(16) unsigned short sT[9][16][128];  // 36864 B
    const int tile = blockIdx.x;
    const int n0   = tile * SAMP;
    const int tid  = threadIdx.x;

    // transpose + convert (col/u map verified r4)
    for (int e = tid; e < SAMP * (SROW / 4); e += 256) {
        int n  = e / 288;
        int c4 = (e % 288) * 4;
        f32x4 v = (n0 + n < N) ? *(const f32x4*)&x1[(size_t)(n0 + n) * SROW + c4]
                               : (f32x4)(0.0f);
        #pragma unroll
        for (int j = 0; j < 4; ++j) {
            int c = c4 + j;
            int col, u;
            if (c < 128)       { col = 0;           u = c; }
            else if (c < 512)  { int rr = c - 128;  u = rr / 3; col = 1 + rr % 3; }
            else               { int rr = c - 512;  u = rr / 5; col = 4 + rr % 5; }
            sT[col][n][u] = f2bf(v[j]);
        }
    }
    __syncthreads();

    // fragment-major copy LDS -> global tile image (coalesced 16B stores)
    char* dst = xT + (size_t)tile * xstride;
    for (int e = tid; e < 9 * 4 * 64; e += 256) {
        int col  = e >> 8;
        int ub   = (e >> 6) & 3;
        int lane = e & 63;
        int r16 = lane & 15, q4 = lane >> 4;
        const unsigned short* s = &sT[col][r16][ub * 32 + q4 * 8];
        *(f32x4*)(dst + e * 16) = *(const f32x4*)s;
    }
}

// ---------------- sM35 staging (verified r4, byte-identical) -----------------
__device__ __forceinline__ void stage_m35(
    const float* __restrict__ x2, int n0, int N, float* sM35, int tid)
{
    for (int e = tid; e < SAMP * 115; e += NTHREADS) {
        int n = e / 115, m = e % 115;
        float val = 0.0f;
        int pi5 = 0;
        #pragma unroll
        for (int p = 0; p < NPATH; ++p) {
            if (m >= H_MOFF[p] && m < H_MOFF[p + 1]) {
                const int n2 = H_N2[p], n3 = H_N3[p];
                int rr = m - H_MOFF[p];
                int i = rr / n3, k = rr % n3;
                if (n0 + n < N) {
                    const float* Cp  = c_W3.v + H_W3OFF[p];
                    const float* x2p = x2 + (size_t)(n0 + n) * 9 + H_X2OFF[H_L2[p]];
                    float a = 0.0f;
                    #pragma unroll
                    for (int j = 0; j < n2; ++j)
                        a += Cp[(i * n2 + j) * n3 + k] * x2p[j];
                    val = H_PW[H_LO[p]] * a;
                }
                pi5 = (H_PIB[p] + i) * 5 + k;
            }
        }
        sM35[n * 175 + pi5] = val;
    }
}

// ---------------- GEMM pass: B from global; RUNTIME ub loop (code-size) ------
// Indices verified r7/r8/r11/r19. Single change vs r19: the ub dimension is a
// runtime loop (4x less instruction footprint); acc indices stay compile-time.
template<int P0G, int NP, int CB, int NC>
__device__ __forceinline__ void gemm_pass(
    const unsigned short* __restrict__ whi,
    const char* __restrict__ xt,      // fragment-major tile base
    const float* sM35,
    float (&ov)[4][9], int r16, int q4, int wt, int lane)
{
    f32x4 acc[NP][NC];
    #pragma unroll
    for (int pp = 0; pp < NP; ++pp)
        #pragma unroll
        for (int i = 0; i < NC; ++i) acc[pp][i] = (f32x4)(0.0f);

    const char* xbase = xt + ((CB * 4) << 10) + lane * 16;
    const unsigned short* abase =
        whi + ((size_t)(P0G * 128 + wt * 16 + r16)) * 128 + q4 * 8;

    for (int ub = 0; ub < 4; ++ub) {   // runtime loop: 4x smaller code
        bf16x8 B[NC];
        #pragma unroll
        for (int c = 0; c < NC; ++c)
            B[c] = *(const bf16x8*)(xbase + ((c * 4 + ub) << 10));
        #pragma unroll
        for (int pp = 0; pp < NP; ++pp) {
            bf16x8 Ah = *(const bf16x8*)(abase + (size_t)pp * 16384 + ub * 32);
            #pragma unroll
            for (int i = 0; i < NC; ++i)
                acc[pp][i] = MFMA(Ah, B[i], acc[pp][i]);
        }
    }

    #pragma unroll
    for (int pp = 0; pp < NP; ++pp) {
        const int P = P0G + pp;
        #pragma unroll
        for (int i = 0; i < NC; ++i)
            #pragma unroll
            for (int k = 0; k < H_N3[P]; ++k) {
                const float mv = sM35[r16 * 175 + (H_PIB[P] + i) * 5 + k];
                #pragma unroll
                for (int r = 0; r < 4; ++r)
                    ov[r][H_KCB[H_LO[P]] + k] += acc[pp][i][r] * mv;
            }
    }
}

// ---------------- main kernel: r19 flow, compact code ------------------------
// LDS union: sM35 (11200 B, live during GEMM) then sOut[16][1156] (73984 B).
__global__ __launch_bounds__(NTHREADS, 1) void fctp_kernel(
    const float* __restrict__ x2,
    const unsigned short* __restrict__ whi,
    const char* __restrict__ xT, long xstride,
    float* __restrict__ out, int N)
{
    __shared__ __align__(16) unsigned char smem[73984];
    float* sM35 = (float*)smem;

    const int tid  = threadIdx.x;
    const int lane = tid & 63;
    const int wt   = tid >> 6;
    const int r16  = lane & 15;
    const int q4   = lane >> 4;
    const int tile = blockIdx.x;
    const int n0   = tile * SAMP;
    const char* xt = xT + (size_t)tile * xstride;

    // ---- stage sM35 only ----
    stage_m35(x2, n0, N, sM35, tid);
    __syncthreads();

    // ---- MFMA GEMM in 5 l1-homogeneous passes, B from global/L1 ----
    float ov[4][9];
    #pragma unroll
    for (int r = 0; r < 4; ++r)
        #pragma unroll
        for (int j = 0; j < 9; ++j) ov[r][j] = 0.0f;

    gemm_pass<0, 3, 0, 1>(whi, xt, sM35, ov, r16, q4, wt, lane);  // p0-2
    gemm_pass<3, 2, 1, 3>(whi, xt, sM35, ov, r16, q4, wt, lane);  // p3,4
    gemm_pass<5, 2, 1, 3>(whi, xt, sM35, ov, r16, q4, wt, lane);  // p5,6
    gemm_pass<7, 2, 4, 5>(whi, xt, sM35, ov, r16, q4, wt, lane);  // p7,8
    gemm_pass<9, 2, 4, 5>(whi, xt, sM35, ov, r16, q4, wt, lane);  // p9,10

    // ---- single-phase epilogue: sOut[16][1156] aliases the union ----
    __syncthreads();   // all sM35 reads complete
    float* sOut = (float*)smem;
    {
        const int wbase = wt * 16 + q4 * 4;
        float* so = &sOut[r16 * 1156];
        #pragma unroll
        for (int r = 0; r < 4; ++r) {
            const int w = wbase + r;
            so[w] = ov[r][0];
            #pragma unroll
            for (int kk = 0; kk < 3; ++kk) so[128 + w * 3 + kk] = ov[r][1 + kk];
            #pragma unroll
            for (int kk = 0; kk < 5; ++kk) so[512 + w * 5 + kk] = ov[r][4 + kk];
        }
    }
    __syncthreads();

    for (int e = tid; e < SAMP * (SROW / 4); e += NTHREADS) {
        int nn = e / (SROW / 4), c4 = (e % (SROW / 4)) * 4;
        int gn = n0 + nn;
        if (gn < N)
            *(f32x4*)&out[(size_t)gn * SROW + c4] =
                *(const f32x4*)&sOut[nn * 1156 + c4];
    }
}

// ---------------- launch -----------------------------------------------------
extern "C" void kernel_launch(void* const* d_in, const int* in_sizes, int n_in,
                              void* d_out, int out_size, void* d_ws, size_t ws_size,
                              hipStream_t stream) {
    const float* x1 = (const float*)d_in[0];
    const float* x2 = (const float*)d_in[1];
    const float* wt = (const float*)d_in[2];
    float* out = (float*)d_out;

    unsigned short* whi = (unsigned short*)d_ws;

    int N = in_sizes[0] / SROW;
    int ntiles = (N + SAMP - 1) / SAMP;

    size_t whiB = (size_t)NPATH * 128 * 128 * sizeof(unsigned short);
    size_t xtB  = (size_t)ntiles * XT2_TILE_B;
    char* xT;
    long  xstride;
    if (ws_size >= whiB + xtB) {
        xT = (char*)d_ws + whiB;
        xstride = XT2_TILE_B;
    } else {
        // park each tile's image inside its own (not-yet-written) output region;
        // the owning block consumes it before writing that region.
        xT = (char*)d_out;
        xstride = (long)SAMP * SROW * 4;   // 73728 >= 36864
    }

    hipLaunchKernelGGL(wprep_kernel, dim3((NPATH * 128 * 128 + 255) / 256),
                       dim3(256), 0, stream, wt, whi);
    hipLaunchKernelGGL(xprep_kernel, dim3(ntiles), dim3(256), 0, stream,
                       x1, xT, xstride, N);

    hipLaunchKernelGGL(fctp_kernel, dim3(ntiles), dim3(NTHREADS), 0, stream,
                       x2, whi, xT, xstride, out, N);
}